// Round 8
// baseline (35.627 us; speedup 1.0000x reference)
//
#include <hip/hip_runtime.h>
#include <cstdint>

// ---------------------------------------------------------------------------
// TileTask_62277025792545: bit-serial int8 conv emulation.
//   conv: 8 bit-planes of cast_in (two's complement), each 3x3x64->64 conv,
//   per-plane q = 2*clip(rne(y/2),-128,127), recombine with [1,2,..,64,-128],
//   +bias, +merge, quant(cmult), +gather, quant(0.75), relu, quant(1), pool2x2.
// Implementation: implicit-GEMM MFMA (i8), M=(pixel,plane), N=cout, K=ci*9=576.
// R8: B-fragments moved to LDS (evidence: R1 VGPR_Count=124 < Bf's 144 regs ->
// compiler was re-loading B from global/scratch inside the hot loop every
// chunk; that ~250cyc/chunk chain explains the schedule-invariant ~30us).
// K-outer/quad-inner: per chunk read B0,B1 once from LDS, feed 8 MFMAs
// (4 quads x 2 cout halves) into acc[4][2] (128 VGPR, static indices).
// ---------------------------------------------------------------------------

typedef int i32x4  __attribute__((ext_vector_type(4)));
typedef int i32x16 __attribute__((ext_vector_type(16)));

#define XB_OFF   0u
#define XB_BYTES 4326400u                      // 4*130*130*64 u8, padded NHWC
#define WPK_OFF  XB_BYTES                      // packed i8 B-frags
#define WPK_BYTES 36864u                       // 18*2*64*16 i8

// cast_in NCHW f32 -> NHWC bytes with halo (130x130), + weight pack + halo
// row zeroing. Blocks 0..511 cast, 512..655 pack, 656..663 halo rows.
__global__ __launch_bounds__(256) void k_stage(const float* __restrict__ s_cast,
                                               const float* __restrict__ wsrc,
                                               uint8_t* __restrict__ ws) {
  const int blk = blockIdx.x, t = threadIdx.x;
  if (blk >= 656) {                            // ---- halo top/bottom rows ----
    const int hb = blk - 656;                  // 8 blocks: 4 b x {0,129}
    const int b = hb >> 1, r = (hb & 1) ? 129 : 0;
    uint8_t* base = ws + XB_OFF + ((size_t)(b * 130 + r) * 130) * 64;
    const uint4 z = {0, 0, 0, 0};
#pragma unroll
    for (int i = 0; i < 3; ++i) {
      const int s = i * 256 + t;
      if (s < 520) *(uint4*)(base + (size_t)s * 16) = z;   // 520*16 = 8320
    }
    return;
  }
  if (blk >= 512) {                            // ---- weight pack path ----
    const int idx = (blk - 512) * 256 + t;     // covers exactly 36864
    const int i = idx & 15, l = (idx >> 4) & 63, gg = (idx >> 10) & 1,
              c = idx >> 11;                   // c in [0,18)
    const int k = c * 32 + (l >> 5) * 16 + i;  // k = tap*64 + ci
    const int tap = k >> 6, ci = k & 63;
    const int kh = tap / 3, kw = tap % 3;
    const int cco = gg * 32 + (l & 31);
    const float wv = wsrc[((cco * 64 + ci) * 3 + kh) * 3 + kw];
    ((int8_t*)(ws + WPK_OFF))[idx] = (int8_t)(int)wv;
    return;
  }
  const int b = blk >> 7, h = blk & 127;       // ---- cast path ----
  __shared__ uint8_t lds[128 * 68];            // [w][ci], +4 pad for banks
  const float* s0 = s_cast + ((size_t)(b * 64) * 128 + h) * 128;
#pragma unroll
  for (int ci0 = 0; ci0 < 64; ci0 += 2) {
    const int ci = ci0 + (t >> 7), w = t & 127;
    const float v = s0[ci * 16384 + w];        // coalesced over w
    lds[w * 68 + ci] = (uint8_t)((int)v & 0xFF);
  }
  __syncthreads();
  uint8_t* row = ws + XB_OFF + (((size_t)b * 130 + h + 1) * 130) * 64;
#pragma unroll
  for (int j = 0; j < 8; ++j) {                // interior cols 1..128
    const int f = j * 256 + t;
    const int w = f >> 4, ci4 = f & 15;
    const uint32_t val = *(const uint32_t*)&lds[w * 68 + ci4 * 4];
    *(uint32_t*)(row + 64 + (size_t)f * 4) = val;
  }
  if (t < 8) {                                 // side halo cols 0 and 129
    const int col = (t < 4) ? 0 : 129, seg = t & 3;
    const uint4 z = {0, 0, 0, 0};
    *(uint4*)(row + (size_t)col * 64 + seg * 16) = z;
  }
}

__global__ __launch_bounds__(256, 2) void k_main(
    const unsigned char* __restrict__ xb, const float* __restrict__ mgf,
    const float* __restrict__ gtf, const int8_t* __restrict__ wpk,
    const float* __restrict__ bias, const float* __restrict__ cti,
    const float* __restrict__ cts, const float* __restrict__ sti,
    const float* __restrict__ sts, const float* __restrict__ ati,
    const float* __restrict__ ats, float* __restrict__ outp) {
  const int tid = threadIdx.x, lane = tid & 63, wv = tid >> 6;
  const int blk = blockIdx.x;
  const int wq = blk & 3, ho = (blk >> 2) & 63, b = blk >> 8;
  const int h = ho * 2, w0 = wq * 32;          // block: 32 actual w cols

  __shared__ uint4 ldsx4[640];                 // x strip: [4 rows][40 cols][64 ci]
  __shared__ i32x4 wpkl[2304];                 // all B-frags: 36,864 B
  __shared__ uint8_t mgt8[2][2][64][36];       // mg/gt int8: [t][hh][co][w+pad]
  __shared__ float po_lds[16 * 64];            // pooled out: [wo_local][co]
  uint8_t* ldsx = (uint8_t*)ldsx4;

  // ---- stage x rows h..h+3, padded cols w0..w0+33 into LDS ----
  {
    const unsigned char* xrow = xb + ((size_t)(b * 130 + h) * 130 + w0) * 64;
#pragma unroll
    for (int i = 0; i < 3; ++i) {
      const int s = i * 256 + tid;             // 640 x 16B segments
      if (s < 640) {
        const int row = s / 160, rm = s - row * 160;
        const int col = rm >> 2, ci16 = rm & 3;
        const int gcol = col < 34 ? col : 33;  // pad cols: safe duplicate
        const uint4 v =
            *(const uint4*)(xrow + ((size_t)row * 130 + gcol) * 64 + ci16 * 16);
        *(uint4*)(ldsx + (row * 40 + col) * 64 + ci16 * 16) = v;
      }
    }
  }

  // ---- stage ALL B fragments into LDS (36 KB; L2-hot source) ----
#pragma unroll
  for (int i = 0; i < 9; ++i) {
    const int s = i * 256 + tid;               // 2304 16B frags
    wpkl[s] = *(const i32x4*)(wpk + (size_t)s * 16);
  }

  // ---- stage merge/gather as int8 (values int8-exact): [t][hh][co][w] ----
#pragma unroll
  for (int which = 0; which < 2; ++which) {
    const float* sp = which ? gtf : mgf;
#pragma unroll
    for (int i = 0; i < 4; ++i) {
      const int slot = i * 256 + tid;          // 1024 slots
      const int co = slot >> 4, r = slot & 15, hh = r & 1, seg = r >> 1;
      const float4 v = *(const float4*)(
          sp + ((size_t)((b * 64 + co) * 128 + h + hh)) * 128 + w0 + seg * 4);
      const uint32_t pk =
          ((uint32_t)((int)v.x & 0xFF)) | ((uint32_t)((int)v.y & 0xFF) << 8) |
          ((uint32_t)((int)v.z & 0xFF) << 16) | ((uint32_t)((int)v.w & 0xFF) << 24);
      *(uint32_t*)&mgt8[which][hh][co][seg * 4] = pk;
    }
  }

  const int pix = (lane & 31) >> 3;            // A row = pix*8 + plane
  const int plane = lane & 7;
  const int khalf = lane >> 5;
  const int dh = pix >> 1, dw = pix & 1;
  const uint8_t* lbw =
      ldsx + (dh * 40 + dw) * 64 + khalf * 16 + wv * 512;   // + q*128 later

  const int col = lane & 31;                   // cout within half
  const float bs0 = bias[col], bs1 = bias[col + 32];
  const float cm0 = ldexpf(cti[col], (int)cts[col]);        // exact: i * 2^s
  const float cm1 = ldexpf(cti[col + 32], (int)cts[col + 32]);
  const float sm = ldexpf(sti[0], (int)sts[0]);
  const float am = ldexpf(ati[0], (int)ats[0]);
  float pwl[4];                                // this lane's 4 plane weights
  pwl[0] = khalf ? 16.f : 1.f;
  pwl[1] = khalf ? 32.f : 2.f;
  pwl[2] = khalf ? 64.f : 4.f;
  pwl[3] = khalf ? -128.f : 8.f;

  __syncthreads();                             // all LDS tiles ready

  // ---- K-outer, quad-inner: B read once per chunk, feeds 8 MFMAs ----
#define XOFF(c) ((((c) >> 1) / 3) * 2560 + (((c) >> 1) % 3) * 64 + ((c)&1) * 32)
  i32x16 acc[4][2] = {};                       // [quad][g]; static idx (unroll)
#pragma unroll
  for (int c = 0; c < 18; ++c) {               // K = 18 chunks of 32
    const i32x4 B0 = wpkl[(c * 2 + 0) * 64 + lane];
    const i32x4 B1 = wpkl[(c * 2 + 1) * 64 + lane];
#pragma unroll
    for (int q = 0; q < 4; ++q) {
      const uint4 vv = *(const uint4*)(lbw + q * 128 + XOFF(c));
      i32x4 av;                                // bit-plane extract IS the frag
      av[0] = (int)((vv.x >> plane) & 0x01010101u);
      av[1] = (int)((vv.y >> plane) & 0x01010101u);
      av[2] = (int)((vv.z >> plane) & 0x01010101u);
      av[3] = (int)((vv.w >> plane) & 0x01010101u);
      acc[q][0] = __builtin_amdgcn_mfma_i32_32x32x32_i8(av, B0, acc[q][0], 0, 0, 0);
      acc[q][1] = __builtin_amdgcn_mfma_i32_32x32x32_i8(av, B1, acc[q][1], 0, 0, 0);
    }
  }
#undef XOFF

  // ---- epilogue: reg r -> pixel=r>>2, plane=(r&3)+4*khalf ----
#pragma unroll
  for (int q = 0; q < 4; ++q) {
    const int wol = wv * 4 + q;                // 0..15 within block
#pragma unroll
    for (int gg = 0; gg < 2; ++gg) {
      const float bs = gg ? bs1 : bs0;
      const float cm = gg ? cm1 : cm0;
      const int cc = gg * 32 + col;
      float psum[4];
#pragma unroll
      for (int px = 0; px < 4; ++px) {
        float s = 0.f;
#pragma unroll
        for (int j = 0; j < 4; ++j) {
          const float y = (float)acc[q][gg][px * 4 + j];
          const float qq = fminf(fmaxf(rintf(y * 0.5f), -128.f), 127.f);
          s = fmaf(pwl[j], 2.f * qq, s);       // plane_w * 2*clip(rne(y/2))
        }
        psum[px] = s;
      }
#pragma unroll
      for (int px = 0; px < 4; ++px)           // combine plane halves
        psum[px] += __shfl_xor(psum[px], 32);

      float po = -3.0e38f;
#pragma unroll
      for (int px = 0; px < 4; ++px) {
        const int ww = wol * 2 + (px & 1);     // local col 0..31
        const float mgv = (float)(int)(signed char)mgt8[0][px >> 1][cc][ww];
        const float gtv = (float)(int)(signed char)mgt8[1][px >> 1][cc][ww];
        const float x1 = psum[px] + bs + mgv;
        const float x2 = fminf(fmaxf(rintf(x1 * cm), -128.f), 127.f);
        const float x3 = x2 + gtv;
        const float x4 = fminf(fmaxf(rintf(x3 * sm), -128.f), 127.f);
        const float x5 = fmaxf(x4, 0.f);
        const float x6 = fminf(fmaxf(rintf(x5 * am), -128.f), 127.f);
        po = fmaxf(po, x6);                    // 2x2 maxpool, in-lane
      }
      if (lane < 32)
        po_lds[wol * 64 + gg * 32 + col] = po; // conflict-free (stride 1)
    }
  }

  __syncthreads();                             // all 16x64 pooled values ready
  // ---- NCHW store: thread t -> co=t>>2, 4 contiguous wo (one 16B store) ----
  {
    const int tco = tid >> 2, seg = tid & 3;
    float4 v;
    v.x = po_lds[(seg * 4 + 0) * 64 + tco];
    v.y = po_lds[(seg * 4 + 1) * 64 + tco];
    v.z = po_lds[(seg * 4 + 2) * 64 + tco];
    v.w = po_lds[(seg * 4 + 3) * 64 + tco];
    float* dst = outp + (((size_t)(b * 64 + tco)) * 64 + ho) * 64 + wq * 16 + seg * 4;
    *(float4*)dst = v;
  }
}

extern "C" void kernel_launch(void* const* d_in, const int* in_sizes, int n_in,
                              void* d_out, int out_size, void* d_ws, size_t ws_size,
                              hipStream_t stream) {
  const float* cast_in = (const float*)d_in[0];
  const float* merge_in = (const float*)d_in[1];
  const float* gather_in = (const float*)d_in[2];
  const float* conv_w = (const float*)d_in[3];
  const float* conv_b = (const float*)d_in[4];
  const float* cti = (const float*)d_in[5];
  const float* cts = (const float*)d_in[6];
  const float* sti = (const float*)d_in[7];
  const float* sts = (const float*)d_in[8];
  const float* ati = (const float*)d_in[9];
  const float* ats = (const float*)d_in[10];

  uint8_t* ws = (uint8_t*)d_ws;
  uint8_t* xb = ws + XB_OFF;
  int8_t* wpk = (int8_t*)(ws + WPK_OFF);

  k_stage<<<664, 256, 0, stream>>>(cast_in, conv_w, ws);
  k_main<<<1024, 256, 0, stream>>>(xb, merge_in, gather_in, wpk, conv_b, cti,
                                   cts, sti, sts, ati, ats, (float*)d_out);
}